// Round 11
// baseline (615.504 us; speedup 1.0000x reference)
//
#include <hip/hip_runtime.h>
#include <hip/hip_cooperative_groups.h>
#include <hip/hip_bf16.h>

namespace cg = cooperative_groups;

#define NPAT  16384
#define DF    1024
#define BATCH 512
#define CAP   256   // raw candidate slots per column
#define SUP   16    // max support kept after exact filter
#define MAXIT 8

typedef __attribute__((ext_vector_type(8))) short short8v;  // 8 bf16
typedef __attribute__((ext_vector_type(4))) float f32x4;
typedef unsigned short ushortT;

// async global->LDS, 16B per lane; LDS dest = wave-uniform base + lane*16
#define GLD16(gp, lp) __builtin_amdgcn_global_load_lds( \
    (const __attribute__((address_space(1))) void*)(gp), \
    (__attribute__((address_space(3))) void*)(lp), 16, 0, 0)

__device__ __forceinline__ unsigned encf(float f) {
  unsigned u = __float_as_uint(f);
  return (u & 0x80000000u) ? ~u : (u | 0x80000000u);
}
__device__ __forceinline__ float decf(unsigned e) {
  unsigned u = (e & 0x80000000u) ? (e & 0x7FFFFFFFu) : ~e;
  return __uint_as_float(u);
}

// QT[n][k] = Q[k][n]
__global__ void k_transpose(const float* __restrict__ Q, float* __restrict__ QT) {
  __shared__ float tile[32][33];
  int tx = threadIdx.x & 31;
  int ty = threadIdx.x >> 5;
  int n0 = blockIdx.x * 32;
  int k0 = blockIdx.y * 32;
#pragma unroll
  for (int s = 0; s < 4; ++s)
    tile[ty + 8 * s][tx] = Q[(size_t)(k0 + ty + 8 * s) * BATCH + n0 + tx];
  __syncthreads();
#pragma unroll
  for (int s = 0; s < 4; ++s)
    QT[(size_t)(n0 + ty + 8 * s) * DF + k0 + tx] = tile[tx][ty + 8 * s];
}

// fp32 -> (hi bf16, lo bf16 residual): x = hi + lo + O(2^-17 |x|)
__device__ __forceinline__ void bsplit(float x, ushortT& h, ushortT& l) {
  __hip_bfloat16 hb = __float2bfloat16(x);
  float hf = __bfloat162float(hb);
  __hip_bfloat16 lb = __float2bfloat16(x - hf);
  h = *(ushortT*)&hb;
  l = *(ushortT*)&lb;
}

__global__ void k_xsplit(const float4* __restrict__ X4, unsigned* __restrict__ Xh,
                         unsigned* __restrict__ Xl) {
  size_t i = (size_t)blockIdx.x * blockDim.x + threadIdx.x;  // 4 elems/thread
  float4 v = X4[i];
  ushortT h0, h1, h2, h3, l0, l1, l2, l3;
  bsplit(v.x, h0, l0); bsplit(v.y, h1, l1);
  bsplit(v.z, h2, l2); bsplit(v.w, h3, l3);
  Xh[2 * i]     = (unsigned)h0 | ((unsigned)h1 << 16);
  Xh[2 * i + 1] = (unsigned)h2 | ((unsigned)h3 << 16);
  Xl[2 * i]     = (unsigned)l0 | ((unsigned)l1 << 16);
  Xl[2 * i + 1] = (unsigned)l2 | ((unsigned)l3 << 16);
}

// Initial Q split from QT; blocks 0,1 also clear the per-iter counters.
__global__ void k_qsplit0(const float4* __restrict__ QT4, unsigned* __restrict__ Qh,
                          unsigned* __restrict__ Ql, unsigned* __restrict__ colMaxEnc,
                          int* __restrict__ candCount) {
  int t = threadIdx.x;
  if (blockIdx.x < 2) {
    colMaxEnc[blockIdx.x * 256 + t] = 0u;
    candCount[blockIdx.x * 256 + t] = 0;
  }
  size_t i = (size_t)blockIdx.x * blockDim.x + t;
  float4 v = QT4[i];
  ushortT h0, h1, h2, h3, l0, l1, l2, l3;
  bsplit(v.x, h0, l0); bsplit(v.y, h1, l1);
  bsplit(v.z, h2, l2); bsplit(v.w, h3, l3);
  Qh[2 * i]     = (unsigned)h0 | ((unsigned)h1 << 16);
  Qh[2 * i + 1] = (unsigned)h2 | ((unsigned)h3 << 16);
  Ql[2 * i]     = (unsigned)l0 | ((unsigned)l1 << 16);
  Ql[2 * i + 1] = (unsigned)l2 | ((unsigned)l3 << 16);
}

// ===================== FALLBACK PATH (round-9 proven) =====================

__global__ __launch_bounds__(256, 2) void k_gemm(
    const ushortT* __restrict__ Xh, const ushortT* __restrict__ Xl,
    const ushortT* __restrict__ Qh, const ushortT* __restrict__ Ql,
    unsigned* __restrict__ colMaxEnc, int* __restrict__ candCount,
    int* __restrict__ candIdx, float* __restrict__ candVal,
    const int* __restrict__ conv) {
  if (*conv) return;
  __shared__ ushortT Ah[128 * 64], Al[128 * 64], Bh[128 * 64], Bl[128 * 64];
  __shared__ unsigned cmax[128];
  __shared__ float cthr[128];
  const int t  = threadIdx.x;
  const int l  = t & 63;
  const int w  = t >> 6;
  const int wr = w >> 1, wc = w & 1;
  const int lr = l & 15;
  const int lk = l >> 4;
  const int lin = blockIdx.y * 4 + blockIdx.x;          // 512 blocks
  const int nid = (lin & 7) * 64 + (lin >> 3);          // bijective (512%8==0)
  const int bx = nid & 3, by = nid >> 2;
  const int row0 = by * 128, col0 = bx * 128;

  f32x4 acc[4][4];
#pragma unroll
  for (int i = 0; i < 4; ++i)
#pragma unroll
    for (int j = 0; j < 4; ++j) acc[i][j] = (f32x4)0.f;

  int rA[4], sA[4], dstB[4];
#pragma unroll
  for (int i = 0; i < 4; ++i) {
    int id = i * 256 + t;
    int r = id >> 3, c = id & 7;
    rA[i]   = r;
    sA[i]   = ((c ^ (r & 7)) << 3);
    dstB[i] = (i * 256 + (t & 192)) * 8;
  }

  for (int kc = 0; kc < 16; ++kc) {
    int kb = kc * 64;
    __syncthreads();
#pragma unroll
    for (int i = 0; i < 4; ++i) {
      size_t ao = (size_t)(row0 + rA[i]) * DF + kb + sA[i];
      size_t bo = (size_t)(col0 + rA[i]) * DF + kb + sA[i];
      GLD16(Xh + ao, &Ah[dstB[i]]);
      GLD16(Xl + ao, &Al[dstB[i]]);
      GLD16(Qh + bo, &Bh[dstB[i]]);
      GLD16(Ql + bo, &Bl[dstB[i]]);
    }
    __syncthreads();
#pragma unroll
    for (int pass = 0; pass < 3; ++pass) {
      const ushortT* As = (pass == 2) ? Al : Ah;
      const ushortT* Bs = (pass == 1) ? Bl : Bh;
#pragma unroll
      for (int kk = 0; kk < 2; ++kk) {
        short8v af[4], bf[4];
#pragma unroll
        for (int i = 0; i < 4; ++i) {
          int row = wr * 64 + i * 16 + lr;
          int ch = (kk * 4 + lk) ^ (row & 7);
          af[i] = *(const short8v*)(&As[row * 64 + ch * 8]);
        }
#pragma unroll
        for (int j = 0; j < 4; ++j) {
          int col = wc * 64 + j * 16 + lr;
          int ch = (kk * 4 + lk) ^ (col & 7);
          bf[j] = *(const short8v*)(&Bs[col * 64 + ch * 8]);
        }
#pragma unroll
        for (int i = 0; i < 4; ++i)
#pragma unroll
          for (int j = 0; j < 4; ++j)
            acc[i][j] = __builtin_amdgcn_mfma_f32_16x16x32_bf16(af[i], bf[j], acc[i][j], 0, 0, 0);
      }
    }
  }

  __syncthreads();
  if (t < 128) cmax[t] = 0u;
  __syncthreads();
#pragma unroll
  for (int j = 0; j < 4; ++j) {
    float cm = -3.4e38f;
#pragma unroll
    for (int i = 0; i < 4; ++i)
#pragma unroll
      for (int q = 0; q < 4; ++q) cm = fmaxf(cm, acc[i][j][q]);
    cm = fmaxf(cm, __shfl_xor(cm, 16));
    cm = fmaxf(cm, __shfl_xor(cm, 32));
    if (lk == 0) atomicMax(&cmax[wc * 64 + j * 16 + lr], encf(cm));
  }
  __syncthreads();
  if (t < 128) {
    unsigned old = atomicMax(&colMaxEnc[col0 + t], cmax[t]);
    unsigned snap = old > cmax[t] ? old : cmax[t];
    cthr[t] = decf(snap) - 1.0f;
  }
  __syncthreads();
#pragma unroll
  for (int j = 0; j < 4; ++j) {
    int cl = wc * 64 + j * 16 + lr;
    float thr = cthr[cl];
    int gcol = col0 + cl;
#pragma unroll
    for (int i = 0; i < 4; ++i) {
      int rbase = row0 + wr * 64 + i * 16 + lk * 4;
#pragma unroll
      for (int q = 0; q < 4; ++q) {
        float v = acc[i][j][q];
        if (v > thr) {
          int p = atomicAdd(&candCount[gcol], 1);
          if (p < CAP) {
            candIdx[p * BATCH + gcol] = rbase + q;
            candVal[p * BATCH + gcol] = v;
          }
        }
      }
    }
  }
}

__global__ __launch_bounds__(256) void k_post(
    int* __restrict__ candCount, const int* __restrict__ candIdx,
    const float* __restrict__ candVal, unsigned* __restrict__ colMaxEnc,
    int* __restrict__ suppK, int* __restrict__ suppIdx, float* __restrict__ suppP,
    int* __restrict__ prevK, int* __restrict__ prevIdx, float* __restrict__ prevP,
    const float* __restrict__ X, unsigned* __restrict__ Qh, unsigned* __restrict__ Ql,
    int* __restrict__ conv, int* __restrict__ sameCount, int* __restrict__ doneCount,
    int doQupd) {
  if (*conv) return;
  const int b = blockIdx.x;
  const int t = threadIdx.x;
  __shared__ float scv[SUP];
  __shared__ int   sci[SUP];
  __shared__ float scw[SUP];
  __shared__ int scnt, sk;

  int m = candCount[b];
  if (m > CAP) m = CAP;
  float thr = decf(colMaxEnc[b]) - 1.0f;
  if (t == 0) scnt = 0;
  __syncthreads();
  if (t < m) {
    float v = candVal[t * BATCH + b];
    if (v > thr) {
      int p = atomicAdd(&scnt, 1);
      if (p < SUP) { scv[p] = v; sci[p] = candIdx[t * BATCH + b]; }
    }
  }
  __syncthreads();

  if (t == 0) {
    int n = scnt < SUP ? scnt : SUP;
    float cv[SUP]; int ci[SUP];
    for (int j = 0; j < n; ++j) { cv[j] = scv[j]; ci[j] = sci[j]; }
    for (int j = 1; j < n; ++j) {
      float v = cv[j]; int id = ci[j];
      int s = j - 1;
      while (s >= 0 && (cv[s] < v || (cv[s] == v && ci[s] > id))) {
        cv[s + 1] = cv[s]; ci[s + 1] = ci[s]; --s;
      }
      cv[s + 1] = v; ci[s + 1] = id;
    }
    float cum = 0.f; int k = 0; float tau = 0.f;
    for (int j = 0; j < n; ++j) {
      cum += cv[j];
      float tj = (cum - 1.0f) / (float)(j + 1);
      if (cv[j] > tj) { k = j + 1; tau = tj; }
    }
    suppK[b] = k;
    int same = (k == prevK[b]);
    for (int j = 0; j < k; ++j) {
      float p = cv[j] - tau;
      same = same && (ci[j] == prevIdx[b * SUP + j]) && (p == prevP[b * SUP + j]);
      suppIdx[b * SUP + j] = ci[j];
      suppP[b * SUP + j]   = p;
      prevIdx[b * SUP + j] = ci[j];
      prevP[b * SUP + j]   = p;
      scw[j] = p; sci[j] = ci[j];
    }
    prevK[b] = k;
    sk = k;
    colMaxEnc[b] = 0u;
    candCount[b] = 0;
    if (same) atomicAdd(sameCount, 1);
    __threadfence();
    int d = atomicAdd(doneCount, 1);
    if (d == BATCH - 1) {
      __threadfence();
      if (atomicAdd(sameCount, 0) == BATCH) atomicExch(conv, 1);
      atomicExch(sameCount, 0);
      atomicExch(doneCount, 0);
    }
  }
  __syncthreads();

  if (doQupd) {
    int k = sk;
    float a0 = 0.f, a1 = 0.f, a2 = 0.f, a3 = 0.f;
    for (int j = 0; j < k; ++j) {
      float wgt = scw[j];
      const float* xr = X + (size_t)sci[j] * DF;
      a0 += wgt * xr[2 * t];
      a1 += wgt * xr[2 * t + 1];
      a2 += wgt * xr[512 + 2 * t];
      a3 += wgt * xr[512 + 2 * t + 1];
    }
    ushortT h0, h1, h2, h3, l0, l1, l2, l3;
    bsplit(a0, h0, l0); bsplit(a1, h1, l1);
    bsplit(a2, h2, l2); bsplit(a3, h3, l3);
    Qh[b * 512 + t]       = (unsigned)h0 | ((unsigned)h1 << 16);
    Ql[b * 512 + t]       = (unsigned)l0 | ((unsigned)l1 << 16);
    Qh[b * 512 + 256 + t] = (unsigned)h2 | ((unsigned)h3 << 16);
    Ql[b * 512 + 256 + t] = (unsigned)l2 | ((unsigned)l3 << 16);
  }
}

__global__ void k_scatter(const int* __restrict__ suppK, const int* __restrict__ suppIdx,
                          const float* __restrict__ suppP, float* __restrict__ out) {
  int b = blockIdx.x * blockDim.x + threadIdx.x;
  if (b >= BATCH) return;
  int k = suppK[b];
  for (int j = 0; j < k; ++j)
    out[(size_t)suppIdx[b * SUP + j] * BATCH + b] = suppP[b * SUP + j];
}

// ===================== COOPERATIVE FUSED PATH =====================

__global__ __launch_bounds__(256, 2) void k_iter(
    const ushortT* __restrict__ Xh, const ushortT* __restrict__ Xl,
    ushortT* __restrict__ Qh, ushortT* __restrict__ Ql,
    unsigned* __restrict__ colMaxEnc, int* __restrict__ candCount,
    int* __restrict__ candIdx, float* __restrict__ candVal,
    int* __restrict__ prevK, int* __restrict__ prevIdx, float* __restrict__ prevP,
    const float* __restrict__ X, int* __restrict__ sameCount,
    float* __restrict__ out) {
  cg::grid_group grid = cg::this_grid();
  __shared__ ushortT Ah[128 * 64], Al[128 * 64], Bh[128 * 64], Bl[128 * 64];
  __shared__ unsigned cmax[128];
  __shared__ float cthr[128];
  __shared__ float scv[SUP], scw[SUP];
  __shared__ int   sciS[SUP];
  __shared__ int   scnt, sk;

  const int t  = threadIdx.x;
  const int l  = t & 63;
  const int w  = t >> 6;
  const int wr = w >> 1, wc = w & 1;
  const int lr = l & 15;
  const int lk = l >> 4;
  const int lin = blockIdx.x;
  const int nid = (lin & 7) * 64 + (lin >> 3);
  const int bx = nid & 3, by = nid >> 2;
  const int row0 = by * 128, col0 = bx * 128;

  int rA[4], sA[4], dstB[4];
#pragma unroll
  for (int i = 0; i < 4; ++i) {
    int id = i * 256 + t;
    int r = id >> 3, c = id & 7;
    rA[i]   = r;
    sA[i]   = ((c ^ (r & 7)) << 3);
    dstB[i] = (i * 256 + (t & 192)) * 8;
  }

  for (int it = 0; it < MAXIT; ++it) {
    f32x4 acc[4][4];
#pragma unroll
    for (int i = 0; i < 4; ++i)
#pragma unroll
      for (int j = 0; j < 4; ++j) acc[i][j] = (f32x4)0.f;

    for (int kc = 0; kc < 16; ++kc) {
      int kb = kc * 64;
      __syncthreads();
#pragma unroll
      for (int i = 0; i < 4; ++i) {
        size_t ao = (size_t)(row0 + rA[i]) * DF + kb + sA[i];
        size_t bo = (size_t)(col0 + rA[i]) * DF + kb + sA[i];
        GLD16(Xh + ao, &Ah[dstB[i]]);
        GLD16(Xl + ao, &Al[dstB[i]]);
        GLD16(Qh + bo, &Bh[dstB[i]]);
        GLD16(Ql + bo, &Bl[dstB[i]]);
      }
      __syncthreads();
#pragma unroll
      for (int pass = 0; pass < 3; ++pass) {
        const ushortT* As = (pass == 2) ? Al : Ah;
        const ushortT* Bs = (pass == 1) ? Bl : Bh;
#pragma unroll
        for (int kk = 0; kk < 2; ++kk) {
          short8v af[4], bf[4];
#pragma unroll
          for (int i = 0; i < 4; ++i) {
            int row = wr * 64 + i * 16 + lr;
            int ch = (kk * 4 + lk) ^ (row & 7);
            af[i] = *(const short8v*)(&As[row * 64 + ch * 8]);
          }
#pragma unroll
          for (int j = 0; j < 4; ++j) {
            int col = wc * 64 + j * 16 + lr;
            int ch = (kk * 4 + lk) ^ (col & 7);
            bf[j] = *(const short8v*)(&Bs[col * 64 + ch * 8]);
          }
#pragma unroll
          for (int i = 0; i < 4; ++i)
#pragma unroll
            for (int j = 0; j < 4; ++j)
              acc[i][j] = __builtin_amdgcn_mfma_f32_16x16x32_bf16(af[i], bf[j], acc[i][j], 0, 0, 0);
        }
      }
    }

    __syncthreads();
    if (t < 128) cmax[t] = 0u;
    __syncthreads();
#pragma unroll
    for (int j = 0; j < 4; ++j) {
      float cm = -3.4e38f;
#pragma unroll
      for (int i = 0; i < 4; ++i)
#pragma unroll
        for (int q = 0; q < 4; ++q) cm = fmaxf(cm, acc[i][j][q]);
      cm = fmaxf(cm, __shfl_xor(cm, 16));
      cm = fmaxf(cm, __shfl_xor(cm, 32));
      if (lk == 0) atomicMax(&cmax[wc * 64 + j * 16 + lr], encf(cm));
    }
    __syncthreads();
    if (t < 128) {
      unsigned old = atomicMax(&colMaxEnc[col0 + t], cmax[t]);
      unsigned snap = old > cmax[t] ? old : cmax[t];
      cthr[t] = decf(snap) - 1.0f;
    }
    __syncthreads();
#pragma unroll
    for (int j = 0; j < 4; ++j) {
      int cl = wc * 64 + j * 16 + lr;
      float thr = cthr[cl];
      int gcol = col0 + cl;
#pragma unroll
      for (int i = 0; i < 4; ++i) {
        int rbase = row0 + wr * 64 + i * 16 + lk * 4;
#pragma unroll
        for (int q = 0; q < 4; ++q) {
          float v = acc[i][j][q];
          if (v > thr) {
            int p = atomicAdd(&candCount[gcol], 1);
            if (p < CAP) {
              candIdx[p * BATCH + gcol] = rbase + q;
              candVal[p * BATCH + gcol] = v;
            }
          }
        }
      }
    }

    grid.sync();

    {
      const int b = lin;
      int m = candCount[b];
      if (m > CAP) m = CAP;
      float thr = decf(colMaxEnc[b]) - 1.0f;
      if (t == 0) scnt = 0;
      __syncthreads();
      if (t < m) {
        float v = candVal[t * BATCH + b];
        if (v > thr) {
          int p = atomicAdd(&scnt, 1);
          if (p < SUP) { scv[p] = v; sciS[p] = candIdx[t * BATCH + b]; }
        }
      }
      __syncthreads();
      if (t == 0) {
        int n = scnt < SUP ? scnt : SUP;
        float cv[SUP]; int ci[SUP];
        for (int j = 0; j < n; ++j) { cv[j] = scv[j]; ci[j] = sciS[j]; }
        for (int j = 1; j < n; ++j) {
          float v = cv[j]; int id = ci[j];
          int s = j - 1;
          while (s >= 0 && (cv[s] < v || (cv[s] == v && ci[s] > id))) {
            cv[s + 1] = cv[s]; ci[s + 1] = ci[s]; --s;
          }
          cv[s + 1] = v; ci[s + 1] = id;
        }
        float cum = 0.f; int k = 0; float tau = 0.f;
        for (int j = 0; j < n; ++j) {
          cum += cv[j];
          float tj = (cum - 1.0f) / (float)(j + 1);
          if (cv[j] > tj) { k = j + 1; tau = tj; }
        }
        int same = (k == prevK[b]);
        for (int j = 0; j < k; ++j) {
          float p = cv[j] - tau;
          same = same && (ci[j] == prevIdx[b * SUP + j]) && (p == prevP[b * SUP + j]);
          prevIdx[b * SUP + j] = ci[j];
          prevP[b * SUP + j]   = p;
          scw[j]  = p;
          sciS[j] = ci[j];
        }
        prevK[b] = k;
        sk = k;
        colMaxEnc[b] = 0u;
        candCount[b] = 0;
        if (same) atomicAdd(&sameCount[it], 1);
      }
      __syncthreads();
      if (it < MAXIT - 1) {
        int k = sk;
        float a0 = 0.f, a1 = 0.f, a2 = 0.f, a3 = 0.f;
        for (int j = 0; j < k; ++j) {
          float wgt = scw[j];
          const float* xr = X + (size_t)sciS[j] * DF;
          a0 += wgt * xr[2 * t];
          a1 += wgt * xr[2 * t + 1];
          a2 += wgt * xr[512 + 2 * t];
          a3 += wgt * xr[512 + 2 * t + 1];
        }
        ushortT h0, h1, h2, h3, l0, l1, l2, l3;
        bsplit(a0, h0, l0); bsplit(a1, h1, l1);
        bsplit(a2, h2, l2); bsplit(a3, h3, l3);
        unsigned* qh = (unsigned*)Qh;
        unsigned* ql = (unsigned*)Ql;
        qh[b * 512 + t]       = (unsigned)h0 | ((unsigned)h1 << 16);
        ql[b * 512 + t]       = (unsigned)l0 | ((unsigned)l1 << 16);
        qh[b * 512 + 256 + t] = (unsigned)h2 | ((unsigned)h3 << 16);
        ql[b * 512 + 256 + t] = (unsigned)l2 | ((unsigned)l3 << 16);
      }
    }

    grid.sync();

    if (sameCount[it] == BATCH) break;
  }

  if (t < sk) out[(size_t)sciS[t] * BATCH + lin] = scw[t];
}

extern "C" void kernel_launch(void* const* d_in, const int* in_sizes, int n_in,
                              void* d_out, int out_size, void* d_ws, size_t ws_size,
                              hipStream_t stream) {
  const float* X = (const float*)d_in[0];   // [16384][1024]
  const float* Q = (const float*)d_in[1];   // [1024][512]
  float* out = (float*)d_out;               // [16384][512]

  char* ws = (char*)d_ws;
  ushortT*  Xh  = (ushortT*)ws;             ws += (size_t)NPAT * DF * 2;    // 32 MB
  ushortT*  Xl  = (ushortT*)ws;             ws += (size_t)NPAT * DF * 2;    // 32 MB
  float*    QT  = (float*)ws;               ws += (size_t)BATCH * DF * 4;   //  2 MB
  ushortT*  Qh  = (ushortT*)ws;             ws += (size_t)BATCH * DF * 2;   //  1 MB
  ushortT*  Ql  = (ushortT*)ws;             ws += (size_t)BATCH * DF * 2;   //  1 MB
  unsigned* colMaxEnc = (unsigned*)ws;      ws += BATCH * 4;
  int*      candCount = (int*)ws;           ws += BATCH * 4;
  int*      candIdx   = (int*)ws;           ws += BATCH * CAP * 4;          // 512 KB
  float*    candVal   = (float*)ws;         ws += BATCH * CAP * 4;          // 512 KB
  int*      suppK     = (int*)ws;           ws += BATCH * 4;
  int*      suppIdx   = (int*)ws;           ws += BATCH * SUP * 4;
  float*    suppP     = (float*)ws;         ws += BATCH * SUP * 4;
  int*      prevK     = (int*)ws;           ws += BATCH * 4;
  int*      prevIdx   = (int*)ws;           ws += BATCH * SUP * 4;
  float*    prevP     = (float*)ws;         ws += BATCH * SUP * 4;
  int*      conv      = (int*)ws;           ws += 4;
  int*      sameScal  = (int*)ws;           ws += 4;
  int*      doneCount = (int*)ws;           ws += 4;
  int*      coopSame  = (int*)ws;           ws += MAXIT * 4;
  // prevK starts 0xAA-poisoned -> iteration-0 fixed-point check cannot match.

  (void)hipMemsetAsync(d_out, 0, (size_t)out_size * sizeof(float), stream);
  (void)hipMemsetAsync(conv, 0, 12 + MAXIT * 4, stream);  // conv..coopSame

  k_transpose<<<dim3(BATCH / 32, DF / 32), 256, 0, stream>>>(Q, QT);
  k_xsplit<<<NPAT * DF / 4 / 256, 256, 0, stream>>>((const float4*)X, (unsigned*)Xh, (unsigned*)Xl);
  k_qsplit0<<<BATCH * DF / 4 / 256, 256, 0, stream>>>((const float4*)QT, (unsigned*)Qh,
                                                      (unsigned*)Ql, colMaxEnc, candCount);

  const ushortT* aXh = Xh;  const ushortT* aXl = Xl;
  ushortT* aQh = Qh;        ushortT* aQl = Ql;
  unsigned* aCM = colMaxEnc; int* aCC = candCount;
  int* aCI = candIdx;       float* aCV = candVal;
  int* aPK = prevK;         int* aPI = prevIdx;   float* aPP = prevP;
  const float* aX = X;      int* aSC = coopSame;  float* aOut = out;
  void* args[] = {&aXh, &aXl, &aQh, &aQl, &aCM, &aCC, &aCI, &aCV,
                  &aPK, &aPI, &aPP, &aX, &aSC, &aOut};
  hipError_t rc = hipLaunchCooperativeKernel((const void*)k_iter, dim3(512), dim3(256),
                                             args, 0, stream);
  if (rc != hipSuccess) {
    // Proven round-9 multi-kernel path (identical numerics).
    for (int it = 0; it < MAXIT; ++it) {
      k_gemm<<<dim3(4, 128), 256, 0, stream>>>(Xh, Xl, Qh, Ql, colMaxEnc, candCount,
                                               candIdx, candVal, conv);
      k_post<<<BATCH, 256, 0, stream>>>(candCount, candIdx, candVal, colMaxEnc,
                                        suppK, suppIdx, suppP,
                                        prevK, prevIdx, prevP,
                                        X, (unsigned*)Qh, (unsigned*)Ql,
                                        conv, sameScal, doneCount,
                                        it < MAXIT - 1 ? 1 : 0);
    }
    k_scatter<<<2, 256, 0, stream>>>(suppK, suppIdx, suppP, out);
  }
}

// Round 12
// 333.016 us; speedup vs baseline: 1.8483x; 1.8483x over previous
//
#include <hip/hip_runtime.h>
#include <hip/hip_bf16.h>

#define NPAT  16384
#define DF    1024
#define BATCH 512
#define CAP   256   // raw candidate slots per column
#define SUP   16    // max support kept after exact filter
#define MAXIT 8

typedef __attribute__((ext_vector_type(8))) short short8v;  // 8 bf16
typedef __attribute__((ext_vector_type(4))) float f32x4;
typedef unsigned short ushortT;

// async global->LDS, 16B per lane; LDS dest = wave-uniform base + lane*16
#define GLD16(gp, lp) __builtin_amdgcn_global_load_lds( \
    (const __attribute__((address_space(1))) void*)(gp), \
    (__attribute__((address_space(3))) void*)(lp), 16, 0, 0)

__device__ __forceinline__ unsigned encf(float f) {
  unsigned u = __float_as_uint(f);
  return (u & 0x80000000u) ? ~u : (u | 0x80000000u);
}
__device__ __forceinline__ float decf(unsigned e) {
  unsigned u = (e & 0x80000000u) ? (e & 0x7FFFFFFFu) : ~e;
  return __uint_as_float(u);
}

// fp32 -> (hi bf16, lo bf16 residual): x = hi + lo + O(2^-17 |x|)
__device__ __forceinline__ void bsplit(float x, ushortT& h, ushortT& l) {
  __hip_bfloat16 hb = __float2bfloat16(x);
  float hf = __bfloat162float(hb);
  __hip_bfloat16 lb = __float2bfloat16(x - hf);
  h = *(ushortT*)&hb;
  l = *(ushortT*)&lb;
}

__global__ void k_xsplit(const float4* __restrict__ X4, unsigned* __restrict__ Xh,
                         unsigned* __restrict__ Xl) {
  size_t i = (size_t)blockIdx.x * blockDim.x + threadIdx.x;  // 4 elems/thread
  float4 v = X4[i];
  ushortT h0, h1, h2, h3, l0, l1, l2, l3;
  bsplit(v.x, h0, l0); bsplit(v.y, h1, l1);
  bsplit(v.z, h2, l2); bsplit(v.w, h3, l3);
  Xh[2 * i]     = (unsigned)h0 | ((unsigned)h1 << 16);
  Xh[2 * i + 1] = (unsigned)h2 | ((unsigned)h3 << 16);
  Xl[2 * i]     = (unsigned)l0 | ((unsigned)l1 << 16);
  Xl[2 * i + 1] = (unsigned)l2 | ((unsigned)l3 << 16);
}

// Fused: transpose Q [DF][BATCH] -> split bf16 Qh/Ql [BATCH][DF], and clear
// the per-iteration counters (blocks y==0, x<2). Replaces transpose+qsplit0.
__global__ void k_qprep(const float* __restrict__ Q, unsigned* __restrict__ Qh,
                        unsigned* __restrict__ Ql, unsigned* __restrict__ colMaxEnc,
                        int* __restrict__ candCount) {
  __shared__ float tile[32][33];          // tile[k][n], +1 pad
  int tx = threadIdx.x & 31;
  int ty = threadIdx.x >> 5;              // 0..7
  int n0 = blockIdx.x * 32;
  int k0 = blockIdx.y * 32;
  if (blockIdx.y == 0 && blockIdx.x < 2) {
    colMaxEnc[blockIdx.x * 256 + threadIdx.x] = 0u;
    candCount[blockIdx.x * 256 + threadIdx.x] = 0;
  }
#pragma unroll
  for (int s = 0; s < 4; ++s)
    tile[ty + 8 * s][tx] = Q[(size_t)(k0 + ty + 8 * s) * BATCH + n0 + tx];
  __syncthreads();
  int r = threadIdx.x >> 4;               // n-row within tile (0..15)
  int p = threadIdx.x & 15;               // k-pair index (0..15)
#pragma unroll
  for (int s = 0; s < 2; ++s) {
    int rr = r + 16 * s;
    float a = tile[2 * p][rr], b = tile[2 * p + 1][rr];
    ushortT ha, la, hb, lb;
    bsplit(a, ha, la); bsplit(b, hb, lb);
    size_t o = ((size_t)(n0 + rr) * DF + k0) / 2 + p;
    Qh[o] = (unsigned)ha | ((unsigned)hb << 16);
    Ql[o] = (unsigned)la | ((unsigned)lb << 16);
  }
}

// bf16x3 emulated-fp32 GEMM, no Z store, async global_load_lds staging
// (no spill). Per 64-k chunk: stage Xh/Xl/Qh/Ql tiles (64 KB LDS), 3 passes
// (h*h, h*l, l*h), 96 MFMAs per barrier pair. Epilogue: col-max atomics +
// conservative-threshold candidate push (superset; exact filter in k_post).
__global__ __launch_bounds__(256, 2) void k_gemm(
    const ushortT* __restrict__ Xh, const ushortT* __restrict__ Xl,
    const ushortT* __restrict__ Qh, const ushortT* __restrict__ Ql,
    unsigned* __restrict__ colMaxEnc, int* __restrict__ candCount,
    int* __restrict__ candIdx, float* __restrict__ candVal,
    const int* __restrict__ conv) {
  if (*conv) return;
  __shared__ ushortT Ah[128 * 64], Al[128 * 64], Bh[128 * 64], Bl[128 * 64];
  __shared__ unsigned cmax[128];
  __shared__ float cthr[128];
  const int t  = threadIdx.x;
  const int l  = t & 63;
  const int w  = t >> 6;
  const int wr = w >> 1, wc = w & 1;
  const int lr = l & 15;
  const int lk = l >> 4;
  const int lin = blockIdx.y * 4 + blockIdx.x;          // 512 blocks
  const int nid = (lin & 7) * 64 + (lin >> 3);          // bijective (512%8==0)
  const int bx = nid & 3, by = nid >> 2;
  const int row0 = by * 128, col0 = bx * 128;

  f32x4 acc[4][4];
#pragma unroll
  for (int i = 0; i < 4; ++i)
#pragma unroll
    for (int j = 0; j < 4; ++j) acc[i][j] = (f32x4)0.f;

  int rA[4], sA[4], dstB[4];
#pragma unroll
  for (int i = 0; i < 4; ++i) {
    int id = i * 256 + t;
    int r = id >> 3, c = id & 7;
    rA[i]   = r;
    sA[i]   = ((c ^ (r & 7)) << 3);        // pre-swizzled global k-offset
    dstB[i] = (i * 256 + (t & 192)) * 8;   // wave-uniform LDS base (shorts)
  }

  for (int kc = 0; kc < 16; ++kc) {
    int kb = kc * 64;
    __syncthreads();
#pragma unroll
    for (int i = 0; i < 4; ++i) {
      size_t ao = (size_t)(row0 + rA[i]) * DF + kb + sA[i];
      size_t bo = (size_t)(col0 + rA[i]) * DF + kb + sA[i];
      GLD16(Xh + ao, &Ah[dstB[i]]);
      GLD16(Xl + ao, &Al[dstB[i]]);
      GLD16(Qh + bo, &Bh[dstB[i]]);
      GLD16(Ql + bo, &Bl[dstB[i]]);
    }
    __syncthreads();
#pragma unroll
    for (int pass = 0; pass < 3; ++pass) {
      const ushortT* As = (pass == 2) ? Al : Ah;
      const ushortT* Bs = (pass == 1) ? Bl : Bh;
#pragma unroll
      for (int kk = 0; kk < 2; ++kk) {
        short8v af[4], bf[4];
#pragma unroll
        for (int i = 0; i < 4; ++i) {
          int row = wr * 64 + i * 16 + lr;
          int ch = (kk * 4 + lk) ^ (row & 7);
          af[i] = *(const short8v*)(&As[row * 64 + ch * 8]);
        }
#pragma unroll
        for (int j = 0; j < 4; ++j) {
          int col = wc * 64 + j * 16 + lr;
          int ch = (kk * 4 + lk) ^ (col & 7);
          bf[j] = *(const short8v*)(&Bs[col * 64 + ch * 8]);
        }
#pragma unroll
        for (int i = 0; i < 4; ++i)
#pragma unroll
          for (int j = 0; j < 4; ++j)
            acc[i][j] = __builtin_amdgcn_mfma_f32_16x16x32_bf16(af[i], bf[j], acc[i][j], 0, 0, 0);
      }
    }
  }

  __syncthreads();
  if (t < 128) cmax[t] = 0u;
  __syncthreads();
#pragma unroll
  for (int j = 0; j < 4; ++j) {
    float cm = -3.4e38f;
#pragma unroll
    for (int i = 0; i < 4; ++i)
#pragma unroll
      for (int q = 0; q < 4; ++q) cm = fmaxf(cm, acc[i][j][q]);
    cm = fmaxf(cm, __shfl_xor(cm, 16));
    cm = fmaxf(cm, __shfl_xor(cm, 32));
    if (lk == 0) atomicMax(&cmax[wc * 64 + j * 16 + lr], encf(cm));
  }
  __syncthreads();
  if (t < 128) {
    unsigned old = atomicMax(&colMaxEnc[col0 + t], cmax[t]);
    unsigned snap = old > cmax[t] ? old : cmax[t];
    cthr[t] = decf(snap) - 1.0f;          // <= final_max - 1 -> superset push
  }
  __syncthreads();
#pragma unroll
  for (int j = 0; j < 4; ++j) {
    int cl = wc * 64 + j * 16 + lr;
    float thr = cthr[cl];
    int gcol = col0 + cl;
#pragma unroll
    for (int i = 0; i < 4; ++i) {
      int rbase = row0 + wr * 64 + i * 16 + lk * 4;
#pragma unroll
      for (int q = 0; q < 4; ++q) {
        float v = acc[i][j][q];
        if (v > thr) {
          int p = atomicAdd(&candCount[gcol], 1);
          if (p < CAP) {
            candIdx[p * BATCH + gcol] = rbase + q;   // [CAP][BATCH] layout
            candVal[p * BATCH + gcol] = v;
          }
        }
      }
    }
  }
}

// Per-column postprocess: exact filter + sort + tau + fixed-point vote +
// fused Q-update + INCREMENTAL output maintenance (clear old support entries,
// write new ones) -> no separate scatter kernel. Block = column.
__global__ __launch_bounds__(256) void k_post(
    int* __restrict__ candCount, const int* __restrict__ candIdx,
    const float* __restrict__ candVal, unsigned* __restrict__ colMaxEnc,
    int* __restrict__ prevK, int* __restrict__ prevIdx, float* __restrict__ prevP,
    const float* __restrict__ X, unsigned* __restrict__ Qh, unsigned* __restrict__ Ql,
    int* __restrict__ conv, int* __restrict__ sameCount, int* __restrict__ doneCount,
    float* __restrict__ out, int doQupd) {
  if (*conv) return;
  const int b = blockIdx.x;
  const int t = threadIdx.x;
  __shared__ float scv[SUP];
  __shared__ int   sci[SUP];
  __shared__ float scw[SUP];
  __shared__ int scnt, sk;

  int m = candCount[b];
  if (m > CAP) m = CAP;
  float thr = decf(colMaxEnc[b]) - 1.0f;
  if (t == 0) scnt = 0;
  __syncthreads();
  if (t < m) {                            // exact filter: true support is here
    float v = candVal[t * BATCH + b];
    if (v > thr) {
      int p = atomicAdd(&scnt, 1);
      if (p < SUP) { scv[p] = v; sci[p] = candIdx[t * BATCH + b]; }
    }
  }
  __syncthreads();

  if (t == 0) {
    int n = scnt < SUP ? scnt : SUP;
    float cv[SUP]; int ci[SUP];
    for (int j = 0; j < n; ++j) { cv[j] = scv[j]; ci[j] = sci[j]; }
    for (int j = 1; j < n; ++j) {         // sort desc, idx tie-break: determinism
      float v = cv[j]; int id = ci[j];
      int s = j - 1;
      while (s >= 0 && (cv[s] < v || (cv[s] == v && ci[s] > id))) {
        cv[s + 1] = cv[s]; ci[s + 1] = ci[s]; --s;
      }
      cv[s + 1] = v; ci[s + 1] = id;
    }
    float cum = 0.f; int k = 0; float tau = 0.f;
    for (int j = 0; j < n; ++j) {
      cum += cv[j];
      float tj = (cum - 1.0f) / (float)(j + 1);
      if (cv[j] > tj) { k = j + 1; tau = tj; }
    }
    // incremental out: clear previous support entries (prevK poisoned
    // negative on iteration 0 -> loop skipped), then write the new ones.
    int pk = prevK[b];
    for (int j = 0; j < pk && j < SUP; ++j)
      out[(size_t)prevIdx[b * SUP + j] * BATCH + b] = 0.f;
    int same = (k == pk);
    for (int j = 0; j < k; ++j) {
      float p = cv[j] - tau;
      same = same && (ci[j] == prevIdx[b * SUP + j]) && (p == prevP[b * SUP + j]);
      prevIdx[b * SUP + j] = ci[j];
      prevP[b * SUP + j]   = p;
      out[(size_t)ci[j] * BATCH + b] = p;
      scw[j] = p; sci[j] = ci[j];         // for the fused Q-update below
    }
    prevK[b] = k;
    sk = k;
    colMaxEnc[b] = 0u;                    // reset for next iteration's gemm
    candCount[b] = 0;
    // convergence vote: all 512 columns bitwise-identical -> conv=1
    if (same) atomicAdd(sameCount, 1);
    __threadfence();
    int d = atomicAdd(doneCount, 1);
    if (d == BATCH - 1) {                 // last block finalizes + resets
      __threadfence();
      if (atomicAdd(sameCount, 0) == BATCH) atomicExch(conv, 1);
      atomicExch(sameCount, 0);
      atomicExch(doneCount, 0);
    }
  }
  __syncthreads();

  if (doQupd) {                           // Q_{t+1}(:,b) = sum_j p_j X[idx_j,:]
    int k = sk;
    float a0 = 0.f, a1 = 0.f, a2 = 0.f, a3 = 0.f;
    for (int j = 0; j < k; ++j) {
      float wgt = scw[j];
      const float* xr = X + (size_t)sci[j] * DF;
      a0 += wgt * xr[2 * t];
      a1 += wgt * xr[2 * t + 1];
      a2 += wgt * xr[512 + 2 * t];
      a3 += wgt * xr[512 + 2 * t + 1];
    }
    ushortT h0, h1, h2, h3, l0, l1, l2, l3;
    bsplit(a0, h0, l0); bsplit(a1, h1, l1);
    bsplit(a2, h2, l2); bsplit(a3, h3, l3);
    Qh[b * 512 + t]       = (unsigned)h0 | ((unsigned)h1 << 16);
    Ql[b * 512 + t]       = (unsigned)l0 | ((unsigned)l1 << 16);
    Qh[b * 512 + 256 + t] = (unsigned)h2 | ((unsigned)h3 << 16);
    Ql[b * 512 + 256 + t] = (unsigned)l2 | ((unsigned)l3 << 16);
  }
}

extern "C" void kernel_launch(void* const* d_in, const int* in_sizes, int n_in,
                              void* d_out, int out_size, void* d_ws, size_t ws_size,
                              hipStream_t stream) {
  const float* X = (const float*)d_in[0];   // [16384][1024]
  const float* Q = (const float*)d_in[1];   // [1024][512]
  float* out = (float*)d_out;               // [16384][512]

  char* ws = (char*)d_ws;
  ushortT*  Xh  = (ushortT*)ws;             ws += (size_t)NPAT * DF * 2;    // 32 MB
  ushortT*  Xl  = (ushortT*)ws;             ws += (size_t)NPAT * DF * 2;    // 32 MB
  ushortT*  Qh  = (ushortT*)ws;             ws += (size_t)BATCH * DF * 2;   //  1 MB
  ushortT*  Ql  = (ushortT*)ws;             ws += (size_t)BATCH * DF * 2;   //  1 MB
  unsigned* colMaxEnc = (unsigned*)ws;      ws += BATCH * 4;
  int*      candCount = (int*)ws;           ws += BATCH * 4;
  int*      candIdx   = (int*)ws;           ws += BATCH * CAP * 4;          // 512 KB
  float*    candVal   = (float*)ws;         ws += BATCH * CAP * 4;          // 512 KB
  int*      prevK     = (int*)ws;           ws += BATCH * 4;
  int*      prevIdx   = (int*)ws;           ws += BATCH * SUP * 4;
  float*    prevP     = (float*)ws;         ws += BATCH * SUP * 4;
  int*      conv      = (int*)ws;           ws += 4;
  int*      sameCount = (int*)ws;           ws += 4;
  int*      doneCount = (int*)ws;
  // prevK starts 0xAA-poisoned (negative int) -> iteration-0 fixed-point
  // check cannot match and the out-clear loop safely skips.

  (void)hipMemsetAsync(d_out, 0, (size_t)out_size * sizeof(float), stream);
  (void)hipMemsetAsync(conv, 0, 12, stream);   // conv, sameCount, doneCount

  k_xsplit<<<NPAT * DF / 4 / 256, 256, 0, stream>>>((const float4*)X, (unsigned*)Xh, (unsigned*)Xl);
  k_qprep<<<dim3(BATCH / 32, DF / 32), 256, 0, stream>>>(Q, (unsigned*)Qh, (unsigned*)Ql,
                                                         colMaxEnc, candCount);

  for (int it = 0; it < MAXIT; ++it) {
    k_gemm<<<dim3(4, 128), 256, 0, stream>>>(Xh, Xl, Qh, Ql, colMaxEnc, candCount,
                                             candIdx, candVal, conv);
    k_post<<<BATCH, 256, 0, stream>>>(candCount, candIdx, candVal, colMaxEnc,
                                      prevK, prevIdx, prevP,
                                      X, (unsigned*)Qh, (unsigned*)Ql,
                                      conv, sameCount, doneCount,
                                      out, it < MAXIT - 1 ? 1 : 0);
  }
}

// Round 14
// 307.566 us; speedup vs baseline: 2.0012x; 1.0827x over previous
//
#include <hip/hip_runtime.h>
#include <hip/hip_bf16.h>

#define NPAT  16384
#define DF    1024
#define BATCH 512
#define CAP   256   // raw candidate slots per column
#define SUP   16    // max support kept after exact filter
#define MAXIT 8

typedef __attribute__((ext_vector_type(8))) short short8v;  // 8 bf16
typedef __attribute__((ext_vector_type(4))) float f32x4;
typedef unsigned short ushortT;

// async global->LDS, 16B per lane; LDS dest = wave-uniform base + lane*16
#define GLD16(gp, lp) __builtin_amdgcn_global_load_lds( \
    (const __attribute__((address_space(1))) void*)(gp), \
    (__attribute__((address_space(3))) void*)(lp), 16, 0, 0)

__device__ __forceinline__ unsigned encf(float f) {
  unsigned u = __float_as_uint(f);
  return (u & 0x80000000u) ? ~u : (u | 0x80000000u);
}
__device__ __forceinline__ float decf(unsigned e) {
  unsigned u = (e & 0x80000000u) ? (e & 0x7FFFFFFFu) : ~e;
  return __uint_as_float(u);
}

// fp32 -> (hi bf16, lo bf16 residual): x = hi + lo + O(2^-17 |x|)
__device__ __forceinline__ void bsplit(float x, ushortT& h, ushortT& l) {
  __hip_bfloat16 hb = __float2bfloat16(x);
  float hf = __bfloat162float(hb);
  __hip_bfloat16 lb = __float2bfloat16(x - hf);
  h = *(ushortT*)&hb;
  l = *(ushortT*)&lb;
}

__global__ void k_xsplit(const float4* __restrict__ X4, unsigned* __restrict__ Xh,
                         unsigned* __restrict__ Xl) {
  size_t i = (size_t)blockIdx.x * blockDim.x + threadIdx.x;  // 4 elems/thread
  float4 v = X4[i];
  ushortT h0, h1, h2, h3, l0, l1, l2, l3;
  bsplit(v.x, h0, l0); bsplit(v.y, h1, l1);
  bsplit(v.z, h2, l2); bsplit(v.w, h3, l3);
  Xh[2 * i]     = (unsigned)h0 | ((unsigned)h1 << 16);
  Xh[2 * i + 1] = (unsigned)h2 | ((unsigned)h3 << 16);
  Xl[2 * i]     = (unsigned)l0 | ((unsigned)l1 << 16);
  Xl[2 * i + 1] = (unsigned)l2 | ((unsigned)l3 << 16);
}

// Fused: transpose Q [DF][BATCH] -> split bf16 Qh/Ql [BATCH][DF]; blocks
// (y==0, x<2) also clear per-iteration counters and init the active lists.
__global__ void k_qprep(const float* __restrict__ Q, unsigned* __restrict__ Qh,
                        unsigned* __restrict__ Ql, unsigned* __restrict__ colMaxEnc,
                        int* __restrict__ candCount, int* __restrict__ listA,
                        int* __restrict__ cntA, int* __restrict__ cntB) {
  __shared__ float tile[32][33];          // tile[k][n], +1 pad
  int tx = threadIdx.x & 31;
  int ty = threadIdx.x >> 5;              // 0..7
  int n0 = blockIdx.x * 32;
  int k0 = blockIdx.y * 32;
  if (blockIdx.y == 0 && blockIdx.x < 2) {
    int idx = blockIdx.x * 256 + threadIdx.x;
    colMaxEnc[idx] = 0u;
    candCount[idx] = 0;
    listA[idx] = idx;                     // iteration 0: all columns active
    if (idx == 0) { *cntA = BATCH; *cntB = 0; }
  }
#pragma unroll
  for (int s = 0; s < 4; ++s)
    tile[ty + 8 * s][tx] = Q[(size_t)(k0 + ty + 8 * s) * BATCH + n0 + tx];
  __syncthreads();
  int r = threadIdx.x >> 4;               // n-row within tile (0..15)
  int p = threadIdx.x & 15;               // k-pair index (0..15)
#pragma unroll
  for (int s = 0; s < 2; ++s) {
    int rr = r + 16 * s;
    float a = tile[2 * p][rr], b = tile[2 * p + 1][rr];
    ushortT ha, la, hb, lb;
    bsplit(a, ha, la); bsplit(b, hb, lb);
    size_t o = ((size_t)(n0 + rr) * DF + k0) / 2 + p;
    Qh[o] = (unsigned)ha | ((unsigned)hb << 16);
    Ql[o] = (unsigned)la | ((unsigned)lb << 16);
  }
}

// bf16x3 emulated-fp32 GEMM over the ACTIVE column set only (gathered via
// actList). Column tiles >= nAct exit; nAct==0 -> whole kernel is a stub.
// Designated block zeroes the NEXT list's counter (keeps the alternating
// counters consistent through stub iterations). No Z store; async
// global_load_lds staging; 3 passes (h*h,h*l,l*h); col-max + conservative
// candidate push epilogue.
__global__ __launch_bounds__(256, 2) void k_gemm(
    const ushortT* __restrict__ Xh, const ushortT* __restrict__ Xl,
    const ushortT* __restrict__ Qh, const ushortT* __restrict__ Ql,
    unsigned* __restrict__ colMaxEnc, int* __restrict__ candCount,
    int* __restrict__ candIdx, float* __restrict__ candVal,
    const int* __restrict__ actList, const int* __restrict__ cntIn,
    int* __restrict__ cntOut) {
  __shared__ ushortT Ah[128 * 64], Al[128 * 64], Bh[128 * 64], Bl[128 * 64];
  __shared__ unsigned cmax[128];
  __shared__ float cthr[128];
  const int t  = threadIdx.x;
  const int l  = t & 63;
  const int w  = t >> 6;
  const int wr = w >> 1, wc = w & 1;
  const int lr = l & 15;
  const int lk = l >> 4;
  const int lin = blockIdx.y * 4 + blockIdx.x;          // 512 blocks
  const int nid = (lin & 7) * 64 + (lin >> 3);          // bijective (512%8==0)
  const int bx = nid & 3, by = nid >> 2;
  const int row0 = by * 128;

  if (bx == 0 && by == 0 && t == 0) *cntOut = 0;  // before any exit
  const int nAct = *cntIn;
  if (bx * 128 >= nAct) return;                   // inactive column tile

  f32x4 acc[4][4];
#pragma unroll
  for (int i = 0; i < 4; ++i)
#pragma unroll
    for (int j = 0; j < 4; ++j) acc[i][j] = (f32x4)0.f;

  int rA[4], sA[4], dstB[4];
  size_t colB[4];                          // gathered B row bases (shorts)
#pragma unroll
  for (int i = 0; i < 4; ++i) {
    int id = i * 256 + t;
    int r = id >> 3, c = id & 7;
    rA[i]   = r;
    sA[i]   = ((c ^ (r & 7)) << 3);        // pre-swizzled global k-offset
    dstB[i] = (i * 256 + (t & 192)) * 8;   // wave-uniform LDS base (shorts)
    int cc = bx * 128 + r;
    colB[i] = (size_t)actList[cc < nAct ? cc : 0] * DF;
  }

  for (int kc = 0; kc < 16; ++kc) {
    int kb = kc * 64;
    __syncthreads();
#pragma unroll
    for (int i = 0; i < 4; ++i) {
      size_t ao = (size_t)(row0 + rA[i]) * DF + kb + sA[i];
      size_t bo = colB[i] + kb + sA[i];
      GLD16(Xh + ao, &Ah[dstB[i]]);
      GLD16(Xl + ao, &Al[dstB[i]]);
      GLD16(Qh + bo, &Bh[dstB[i]]);
      GLD16(Ql + bo, &Bl[dstB[i]]);
    }
    __syncthreads();
#pragma unroll
    for (int pass = 0; pass < 3; ++pass) {
      const ushortT* As = (pass == 2) ? Al : Ah;
      const ushortT* Bs = (pass == 1) ? Bl : Bh;
#pragma unroll
      for (int kk = 0; kk < 2; ++kk) {
        short8v af[4], bf[4];
#pragma unroll
        for (int i = 0; i < 4; ++i) {
          int row = wr * 64 + i * 16 + lr;
          int ch = (kk * 4 + lk) ^ (row & 7);
          af[i] = *(const short8v*)(&As[row * 64 + ch * 8]);
        }
#pragma unroll
        for (int j = 0; j < 4; ++j) {
          int col = wc * 64 + j * 16 + lr;
          int ch = (kk * 4 + lk) ^ (col & 7);
          bf[j] = *(const short8v*)(&Bs[col * 64 + ch * 8]);
        }
#pragma unroll
        for (int i = 0; i < 4; ++i)
#pragma unroll
          for (int j = 0; j < 4; ++j)
            acc[i][j] = __builtin_amdgcn_mfma_f32_16x16x32_bf16(af[i], bf[j], acc[i][j], 0, 0, 0);
      }
    }
  }

  // epilogue: column max + conservative candidate push (active columns only)
  __syncthreads();
  if (t < 128) cmax[t] = 0u;
  __syncthreads();
#pragma unroll
  for (int j = 0; j < 4; ++j) {
    float cm = -3.4e38f;
#pragma unroll
    for (int i = 0; i < 4; ++i)
#pragma unroll
      for (int q = 0; q < 4; ++q) cm = fmaxf(cm, acc[i][j][q]);
    cm = fmaxf(cm, __shfl_xor(cm, 16));
    cm = fmaxf(cm, __shfl_xor(cm, 32));
    if (lk == 0) atomicMax(&cmax[wc * 64 + j * 16 + lr], encf(cm));
  }
  __syncthreads();
  if (t < 128) {
    int cc = bx * 128 + t;
    if (cc < nAct) {
      int gcol = actList[cc];
      unsigned old = atomicMax(&colMaxEnc[gcol], cmax[t]);
      unsigned snap = old > cmax[t] ? old : cmax[t];
      cthr[t] = decf(snap) - 1.0f;        // <= final_max - 1 -> superset push
    } else {
      cthr[t] = 3.4e38f;                  // padded column: never pushes
    }
  }
  __syncthreads();
#pragma unroll
  for (int j = 0; j < 4; ++j) {
    int cl = wc * 64 + j * 16 + lr;
    float thr = cthr[cl];
    int gcol = actList[bx * 128 + cl];    // in-bounds (<512); used only if push
#pragma unroll
    for (int i = 0; i < 4; ++i) {
      int rbase = row0 + wr * 64 + i * 16 + lk * 4;
#pragma unroll
      for (int q = 0; q < 4; ++q) {
        float v = acc[i][j][q];
        if (v > thr) {
          int p = atomicAdd(&candCount[gcol], 1);
          if (p < CAP) {
            candIdx[p * BATCH + gcol] = rbase + q;   // [CAP][BATCH] layout
            candVal[p * BATCH + gcol] = v;
          }
        }
      }
    }
  }
}

// Per-active-column postprocess: exact filter + sort + tau + incremental out
// maintenance + fixed-point test (changed columns -> next active list) +
// fused Q-update. Block i handles column actList[i]; blocks >= nAct exit.
__global__ __launch_bounds__(256) void k_post(
    int* __restrict__ candCount, const int* __restrict__ candIdx,
    const float* __restrict__ candVal, unsigned* __restrict__ colMaxEnc,
    int* __restrict__ prevK, int* __restrict__ prevIdx, float* __restrict__ prevP,
    const float* __restrict__ X, unsigned* __restrict__ Qh, unsigned* __restrict__ Ql,
    const int* __restrict__ actList, const int* __restrict__ cntIn,
    int* __restrict__ listOut, int* __restrict__ cntOut,
    float* __restrict__ out, int doQupd) {
  const int nAct = *cntIn;
  if ((int)blockIdx.x >= nAct) return;
  const int b = actList[blockIdx.x];      // this block's column
  const int t = threadIdx.x;
  __shared__ float scv[SUP];
  __shared__ int   sci[SUP];
  __shared__ float scw[SUP];
  __shared__ int scnt, sk;

  int m = candCount[b];
  if (m > CAP) m = CAP;
  float thr = decf(colMaxEnc[b]) - 1.0f;
  if (t == 0) scnt = 0;
  __syncthreads();
  if (t < m) {                            // exact filter: true support is here
    float v = candVal[t * BATCH + b];
    if (v > thr) {
      int p = atomicAdd(&scnt, 1);
      if (p < SUP) { scv[p] = v; sci[p] = candIdx[t * BATCH + b]; }
    }
  }
  __syncthreads();

  if (t == 0) {
    int n = scnt < SUP ? scnt : SUP;
    float cv[SUP]; int ci[SUP];
    for (int j = 0; j < n; ++j) { cv[j] = scv[j]; ci[j] = sci[j]; }
    for (int j = 1; j < n; ++j) {         // sort desc, idx tie-break: determinism
      float v = cv[j]; int id = ci[j];
      int s = j - 1;
      while (s >= 0 && (cv[s] < v || (cv[s] == v && ci[s] > id))) {
        cv[s + 1] = cv[s]; ci[s + 1] = ci[s]; --s;
      }
      cv[s + 1] = v; ci[s + 1] = id;
    }
    float cum = 0.f; int k = 0; float tau = 0.f;
    for (int j = 0; j < n; ++j) {
      cum += cv[j];
      float tj = (cum - 1.0f) / (float)(j + 1);
      if (cv[j] > tj) { k = j + 1; tau = tj; }
    }
    // incremental out: clear previous support entries (prevK poisoned
    // negative on iteration 0 -> loop skipped), then write the new ones.
    int pk = prevK[b];
    for (int j = 0; j < pk && j < SUP; ++j)
      out[(size_t)prevIdx[b * SUP + j] * BATCH + b] = 0.f;
    int same = (k == pk);
    for (int j = 0; j < k; ++j) {
      float p = cv[j] - tau;
      same = same && (ci[j] == prevIdx[b * SUP + j]) && (p == prevP[b * SUP + j]);
      prevIdx[b * SUP + j] = ci[j];
      prevP[b * SUP + j]   = p;
      out[(size_t)ci[j] * BATCH + b] = p;
      scw[j] = p; sci[j] = ci[j];         // for the fused Q-update below
    }
    prevK[b] = k;
    sk = k;
    colMaxEnc[b] = 0u;                    // reset for next iteration's gemm
    candCount[b] = 0;
    // changed column -> active next iteration. Unchanged columns are at a
    // provable fixpoint (deterministic per-column pipeline) and drop out.
    if (!same) {
      int pos = atomicAdd(cntOut, 1);
      listOut[pos] = b;
    }
  }
  __syncthreads();

  if (doQupd) {                           // Q_{t+1}(:,b) = sum_j p_j X[idx_j,:]
    int k = sk;
    float a0 = 0.f, a1 = 0.f, a2 = 0.f, a3 = 0.f;
    for (int j = 0; j < k; ++j) {
      float wgt = scw[j];
      const float* xr = X + (size_t)sci[j] * DF;
      a0 += wgt * xr[2 * t];
      a1 += wgt * xr[2 * t + 1];
      a2 += wgt * xr[512 + 2 * t];
      a3 += wgt * xr[512 + 2 * t + 1];
    }
    ushortT h0, h1, h2, h3, l0, l1, l2, l3;
    bsplit(a0, h0, l0); bsplit(a1, h1, l1);
    bsplit(a2, h2, l2); bsplit(a3, h3, l3);
    Qh[b * 512 + t]       = (unsigned)h0 | ((unsigned)h1 << 16);
    Ql[b * 512 + t]       = (unsigned)l0 | ((unsigned)l1 << 16);
    Qh[b * 512 + 256 + t] = (unsigned)h2 | ((unsigned)h3 << 16);
    Ql[b * 512 + 256 + t] = (unsigned)l2 | ((unsigned)l3 << 16);
  }
}

extern "C" void kernel_launch(void* const* d_in, const int* in_sizes, int n_in,
                              void* d_out, int out_size, void* d_ws, size_t ws_size,
                              hipStream_t stream) {
  const float* X = (const float*)d_in[0];   // [16384][1024]
  const float* Q = (const float*)d_in[1];   // [1024][512]
  float* out = (float*)d_out;               // [16384][512]

  char* ws = (char*)d_ws;
  ushortT*  Xh  = (ushortT*)ws;             ws += (size_t)NPAT * DF * 2;    // 32 MB
  ushortT*  Xl  = (ushortT*)ws;             ws += (size_t)NPAT * DF * 2;    // 32 MB
  ushortT*  Qh  = (ushortT*)ws;             ws += (size_t)BATCH * DF * 2;   //  1 MB
  ushortT*  Ql  = (ushortT*)ws;             ws += (size_t)BATCH * DF * 2;   //  1 MB
  unsigned* colMaxEnc = (unsigned*)ws;      ws += BATCH * 4;
  int*      candCount = (int*)ws;           ws += BATCH * 4;
  int*      candIdx   = (int*)ws;           ws += BATCH * CAP * 4;          // 512 KB
  float*    candVal   = (float*)ws;         ws += BATCH * CAP * 4;          // 512 KB
  int*      prevK     = (int*)ws;           ws += BATCH * 4;
  int*      prevIdx   = (int*)ws;           ws += BATCH * SUP * 4;
  float*    prevP     = (float*)ws;         ws += BATCH * SUP * 4;
  int*      listA     = (int*)ws;           ws += BATCH * 4;
  int*      listB     = (int*)ws;           ws += BATCH * 4;
  int*      cntA      = (int*)ws;           ws += 4;
  int*      cntB      = (int*)ws;
  // prevK starts 0xAA-poisoned (negative int) -> iteration-0 fixed-point
  // check cannot match and the out-clear loop safely skips.

  (void)hipMemsetAsync(d_out, 0, (size_t)out_size * sizeof(float), stream);

  k_xsplit<<<NPAT * DF / 4 / 256, 256, 0, stream>>>((const float4*)X, (unsigned*)Xh, (unsigned*)Xl);
  k_qprep<<<dim3(BATCH / 32, DF / 32), 256, 0, stream>>>(Q, (unsigned*)Qh, (unsigned*)Ql,
                                                         colMaxEnc, candCount,
                                                         listA, cntA, cntB);

  for (int it = 0; it < MAXIT; ++it) {
    int*  inList  = (it & 1) ? listB : listA;
    int*  inCnt   = (it & 1) ? cntB  : cntA;
    int*  outList = (it & 1) ? listA : listB;
    int*  outCnt  = (it & 1) ? cntA  : cntB;
    k_gemm<<<dim3(4, 128), 256, 0, stream>>>(Xh, Xl, Qh, Ql, colMaxEnc, candCount,
                                             candIdx, candVal,
                                             inList, inCnt, outCnt);
    k_post<<<BATCH, 256, 0, stream>>>(candCount, candIdx, candVal, colMaxEnc,
                                      prevK, prevIdx, prevP,
                                      X, (unsigned*)Qh, (unsigned*)Ql,
                                      inList, inCnt, outList, outCnt,
                                      out, it < MAXIT - 1 ? 1 : 0);
  }
}